// Round 2
// baseline (22495.717 us; speedup 1.0000x reference)
//
#include <hip/hip_runtime.h>
#include <math.h>

// B=2, MELS=128, CTX=1500, DIMS=1024, HEAD=16, HD=64, LAYER=4, NSAMP=150000
#define CTXN 1500
#define DIMSN 1024

__device__ __forceinline__ float gelu_f(float x) {
    float x3 = x * x * x;
    float t = tanhf(0.7978845608028654f * (x + 0.044715f * x3));
    return 0.5f * x * (1.0f + t);
}

__global__ void sentinel_k(float* out, float v) { out[0] = v; }

// ---------------- tiled implicit-GEMM conv1d  out[b,oc,t] ----------------
// block 256, tile 64(oc) x 64(t), 4x4 microtile, IC chunked by 16
template<int KS, int SPAN, int ACT>
__global__ __launch_bounds__(256) void conv1d_t(
    const float* __restrict__ in, const float* __restrict__ wt,
    const float* __restrict__ bias, float* __restrict__ out,
    int IC, int Tin, int Tout, int stride, int dil, int pad) {
    __shared__ float Ws[16][KS][65];
    __shared__ float Gs[16][SPAN];
    int tid = threadIdx.x;
    int t0 = blockIdx.x * 64;
    int oc0 = blockIdx.y * 64;
    int b = blockIdx.z;
    int tx = tid & 15, ty = tid >> 4;
    float acc[4][4] = {{0.f}};
    int tbase = t0 * stride - pad;
    for (int ic0 = 0; ic0 < IC; ic0 += 16) {
        for (int idx = tid; idx < 64 * 16 * KS; idx += 256) {
            int o = idx / (16 * KS); int r = idx - o * 16 * KS;
            int i = r / KS; int j = r - i * KS;
            Ws[i][j][o] = wt[(size_t)(oc0 + o) * IC * KS + (size_t)(ic0 + i) * KS + j];
        }
        for (int idx = tid; idx < 16 * SPAN; idx += 256) {
            int i = idx / SPAN; int s = idx - i * SPAN;
            int ti = tbase + s;
            Gs[i][s] = (ti >= 0 && ti < Tin) ? in[((size_t)b * IC + ic0 + i) * Tin + ti] : 0.f;
        }
        __syncthreads();
#pragma unroll
        for (int i = 0; i < 16; i++) {
            float wv[4][KS];
#pragma unroll
            for (int o = 0; o < 4; o++)
#pragma unroll
                for (int j = 0; j < KS; j++) wv[o][j] = Ws[i][j][ty * 4 + o];
#pragma unroll
            for (int tj = 0; tj < 4; tj++) {
                int gb = (tx * 4 + tj) * stride;
#pragma unroll
                for (int j = 0; j < KS; j++) {
                    float g = Gs[i][gb + j * dil];
#pragma unroll
                    for (int o = 0; o < 4; o++) acc[o][tj] += wv[o][j] * g;
                }
            }
        }
        __syncthreads();
    }
#pragma unroll
    for (int o = 0; o < 4; o++) {
        int oc = oc0 + ty * 4 + o;
        float bz = bias[oc];
#pragma unroll
        for (int tj = 0; tj < 4; tj++) {
            int t = t0 + tx * 4 + tj;
            if (t < Tout) {
                float v = acc[o][tj] + bz;
                if (ACT == 1) v = gelu_f(v);
                out[((size_t)b * DIMSN + oc) * Tout + t] = v;
            }
        }
    }
}

// -------- fused waveform stem: conv(k11,s5,p5)+gelu -> conv(k5,s2,p2)+gelu -> mean10
// writes P[b, ct, oc] ([B, CTX, D]), already divided by 10.
// block 256: 64 oc x 8 ct. grid (188, 16, 2).
__global__ __launch_bounds__(256) void we_fused_k(
    const float* __restrict__ wav, const float* __restrict__ w1,
    const float* __restrict__ b1, const float* __restrict__ w2,
    const float* __restrict__ b2, float* __restrict__ P) {
    __shared__ float wavs[832];
    __shared__ float g1s[16][164];      // t1rel 0..162
    __shared__ float w2s[16][5][64];
    int tid = threadIdx.x;
    int ct0 = blockIdx.x * 8;
    int oc0 = blockIdx.y * 64;
    int b = blockIdx.z;
    int tx = tid & 63;                  // oc lane
    int ty = tid >> 6;                  // 0..3 -> 2 ct each
    // wav segment: samples [100*ct0-15, 100*ct0+805]
    int wavbase = 100 * ct0 - 15;
    const float* wv = wav + (size_t)b * 150000;
    for (int s = tid; s < 832; s += 256) {
        int wi = wavbase + s;
        wavs[s] = (wi >= 0 && wi < 150000) ? wv[wi] : 0.f;
    }
    float acc[2][10];
#pragma unroll
    for (int c = 0; c < 2; c++)
#pragma unroll
        for (int q = 0; q < 10; q++) acc[c][q] = 0.f;
    int t1base = 20 * ct0 - 2;
    for (int ic0 = 0; ic0 < 1024; ic0 += 16) {
        __syncthreads();
        // stage g1 tile: g1[ic, t1rel] for t1 = t1base + t1rel, zero outside [0,30000)
        for (int e = tid; e < 16 * 163; e += 256) {
            int ic = e / 163, t1r = e - ic * 163;
            int t1 = t1base + t1r;
            float a = 0.f;
            if (t1 >= 0 && t1 < 30000) {
                a = b1[ic0 + ic];
                const float* ww = w1 + (ic0 + ic) * 11;
                int sbase = 5 * t1r;   // t1*5-5 - wavbase
#pragma unroll
                for (int j = 0; j < 11; j++) a += ww[j] * wavs[sbase + j];
                a = gelu_f(a);
            }
            g1s[ic][t1r] = a;
        }
        // stage conv2 weights [ic][k][oc]
        for (int e = tid; e < 16 * 5 * 64; e += 256) {
            int ic = e / 320; int r = e - ic * 320; int k = r >> 6; int oc = r & 63;
            w2s[ic][k][oc] = w2[((size_t)(oc0 + oc) * 1024 + (ic0 + ic)) * 5 + k];
        }
        __syncthreads();
#pragma unroll
        for (int ic = 0; ic < 16; ic++)
#pragma unroll
            for (int k = 0; k < 5; k++) {
                float w = w2s[ic][k][tx];
#pragma unroll
                for (int c = 0; c < 2; c++) {
                    int t2b = (ty * 2 + c) * 10;
#pragma unroll
                    for (int q = 0; q < 10; q++)
                        acc[c][q] += w * g1s[ic][2 * (t2b + q) + k];
                }
            }
    }
    float bz = b2[oc0 + tx];
#pragma unroll
    for (int c = 0; c < 2; c++) {
        int ct = ct0 + ty * 2 + c;
        if (ct < CTXN) {
            float s = 0.f;
#pragma unroll
            for (int q = 0; q < 10; q++) s += gelu_f(acc[c][q] + bz);
            P[((size_t)(b * CTXN) + ct) * DIMSN + oc0 + tx] = s * 0.1f;
        }
    }
}

// ---------------- NT GEMM: C[m,n] = res1 + res2 + act(bias + A[m,:]·W[n,:]) ---
// A [M,K] rowmajor, W [N,K] rowmajor. block 256, 64x64 tile, BK=32, 4x4 micro.
__global__ __launch_bounds__(256) void gemm_nt_k(
    const float* __restrict__ A, const float* __restrict__ W,
    const float* __restrict__ bias, const float* __restrict__ res1,
    const float* __restrict__ res2, float* __restrict__ C,
    int M, int N, int Kd, int act) {
    __shared__ float As[32][68];
    __shared__ float Bs[32][68];
    int tid = threadIdx.x;
    int n0 = blockIdx.x * 64, m0 = blockIdx.y * 64;
    int tx = tid & 15, ty = tid >> 4;
    int lr = tid >> 2;
    int lk = (tid & 3) * 4;
    float acc[4][4] = {{0.f}};
    for (int k0 = 0; k0 < Kd; k0 += 32) {
        int am = m0 + lr;
        float4 a1, a2;
        if (am < M) {
            a1 = *reinterpret_cast<const float4*>(&A[(size_t)am * Kd + k0 + lk]);
            a2 = *reinterpret_cast<const float4*>(&A[(size_t)am * Kd + k0 + lk + 16]);
        } else { a1 = make_float4(0,0,0,0); a2 = a1; }
        float4 w1 = *reinterpret_cast<const float4*>(&W[(size_t)(n0 + lr) * Kd + k0 + lk]);
        float4 w2 = *reinterpret_cast<const float4*>(&W[(size_t)(n0 + lr) * Kd + k0 + lk + 16]);
        As[lk + 0][lr] = a1.x; As[lk + 1][lr] = a1.y; As[lk + 2][lr] = a1.z; As[lk + 3][lr] = a1.w;
        As[lk + 16][lr] = a2.x; As[lk + 17][lr] = a2.y; As[lk + 18][lr] = a2.z; As[lk + 19][lr] = a2.w;
        Bs[lk + 0][lr] = w1.x; Bs[lk + 1][lr] = w1.y; Bs[lk + 2][lr] = w1.z; Bs[lk + 3][lr] = w1.w;
        Bs[lk + 16][lr] = w2.x; Bs[lk + 17][lr] = w2.y; Bs[lk + 18][lr] = w2.z; Bs[lk + 19][lr] = w2.w;
        __syncthreads();
#pragma unroll
        for (int kk = 0; kk < 32; kk++) {
            float4 a4 = *reinterpret_cast<const float4*>(&As[kk][ty * 4]);
            float4 b4 = *reinterpret_cast<const float4*>(&Bs[kk][tx * 4]);
            float aa[4] = {a4.x, a4.y, a4.z, a4.w};
            float bb[4] = {b4.x, b4.y, b4.z, b4.w};
#pragma unroll
            for (int i = 0; i < 4; i++)
#pragma unroll
                for (int j = 0; j < 4; j++) acc[i][j] += aa[i] * bb[j];
        }
        __syncthreads();
    }
#pragma unroll
    for (int i = 0; i < 4; i++) {
        int m = m0 + ty * 4 + i;
        if (m >= M) continue;
#pragma unroll
        for (int j = 0; j < 4; j++) {
            int n = n0 + tx * 4 + j;
            float v = acc[i][j];
            if (bias) v += bias[n];
            if (act == 1) v = fmaxf(v, 0.f);
            size_t off = (size_t)m * N + n;
            if (res1) v += res1[off];
            if (res2) v += res2[off];
            C[off] = v;
        }
    }
}

// ---------------- small elementwise / stem kernels ----------------
__global__ void dwconv_k(const float* __restrict__ in, const float* __restrict__ w3,
                         const float* __restrict__ b3, float* __restrict__ out) {
    int idx = blockIdx.x * 256 + threadIdx.x;           // 2*1024*1500
    int t = idx % CTXN;
    int bc = idx / CTXN;
    int c = bc & 1023;
    float acc = b3[c];
#pragma unroll
    for (int j = 0; j < 3; j++) {
        int ti = t - 1 + j;
        if (ti >= 0 && ti < CTXN) acc += w3[c * 3 + j] * in[(size_t)bc * CTXN + ti];
    }
    out[idx] = acc;
}

__global__ void se_mean_k(const float* __restrict__ in, float* __restrict__ y0) {
    int bc = blockIdx.x; int lane = threadIdx.x;        // 64
    float acc = 0.f;
    for (int t = lane; t < CTXN; t += 64) acc += in[(size_t)bc * CTXN + t];
#pragma unroll
    for (int off = 32; off > 0; off >>= 1) acc += __shfl_xor(acc, off);
    if (lane == 0) y0[bc] = acc / 1500.f;
}

__global__ void se_fc1_k(const float* __restrict__ y0, const float* __restrict__ w,
                         const float* __restrict__ b, float* __restrict__ y1) {
    int tid = threadIdx.x;                               // 128 = 2b x 64n
    int bb = tid >> 6, n = tid & 63;
    float acc = b[n];
    for (int k = 0; k < 1024; k++) acc += y0[bb * 1024 + k] * w[n * 1024 + k];
    y1[bb * 64 + n] = fmaxf(acc, 0.f);
}

__global__ void se_fc2_k(const float* __restrict__ y1, const float* __restrict__ w,
                         const float* __restrict__ b, float* __restrict__ y2) {
    int idx = blockIdx.x * 256 + threadIdx.x;            // 2048
    int bb = idx >> 10, c = idx & 1023;
    float acc = b[c];
#pragma unroll
    for (int k = 0; k < 64; k++) acc += y1[bb * 64 + k] * w[c * 64 + k];
    y2[idx] = 1.f / (1.f + expf(-acc));
}

__global__ void se_scale_k(const float* __restrict__ in, const float* __restrict__ y2,
                           float* __restrict__ out) {
    int idx = blockIdx.x * 256 + threadIdx.x;            // 2*1024*1500
    int bc = idx / CTXN;
    out[idx] = gelu_f(in[idx] * y2[bc]);
}

// h[b,t,d] = blend*xs[b,d,t] + (1-blend)*P[b,t,d] + sinusoid(t,d)
__global__ void blend_k(const float* __restrict__ H6, const float* __restrict__ P,
                        const float* __restrict__ bsw, float* __restrict__ Hs) {
    int idx = blockIdx.x * 256 + threadIdx.x;            // 2*1500*1024
    int d = idx & 1023;
    int rest = idx >> 10;                                // b*1500 + t
    int t = rest % CTXN;
    int b = rest / CTXN;
    float xs = H6[((size_t)b * DIMSN + d) * CTXN + t];
    float wsv = P[idx];
    float bl = 1.f / (1.f + expf(-bsw[0]));
    // inc = ln(10000)/511
    float pos;
    if (d < 512) {
        float inv = expf(-0.018024149455921103f * (float)d);
        pos = sinf((float)t * inv);
    } else {
        float inv = expf(-0.018024149455921103f * (float)(d - 512));
        pos = cosf((float)t * inv);
    }
    Hs[idx] = bl * xs + (1.f - bl) * wsv + pos;
}

__global__ __launch_bounds__(256) void rmsnorm_k(const float* __restrict__ X,
    const float* __restrict__ Wt, float* __restrict__ Y) {
    int row = blockIdx.x; int tid = threadIdx.x;
    const float* x = X + (size_t)row * DIMSN;
    float ss = 0.f;
    for (int d = tid; d < DIMSN; d += 256) { float v = x[d]; ss += v * v; }
    __shared__ float red[256];
    red[tid] = ss; __syncthreads();
    for (int s = 128; s > 0; s >>= 1) { if (tid < s) red[tid] += red[tid + s]; __syncthreads(); }
    float r = rsqrtf(red[0] / (float)DIMSN + 1e-8f);
    float* y = Y + (size_t)row * DIMSN;
    for (int d = tid; d < DIMSN; d += 256) y[d] = x[d] * r * Wt[d];
}

// in-place rotate-half RoPE on Q and K ([B*CTX, DIMS] layout, per head HD=64)
__global__ void rope_k(float* __restrict__ Qp, float* __restrict__ Kp) {
    int idx = blockIdx.x * 256 + threadIdx.x;            // 2*1500*16*32
    int d = idx & 31;
    int h = (idx >> 5) & 15;
    int row = idx >> 9;                                  // b*CTX + t
    int t = row % CTXN;
    float inv = 1.0f / powf(10000.0f, (float)d / 32.0f);
    float fr = (float)t * inv;
    float sn, cs;
    sincosf(fr, &sn, &cs);
    size_t base = (size_t)row * DIMSN + h * 64 + d;
    float q1 = Qp[base], q2 = Qp[base + 32];
    Qp[base] = q1 * cs - q2 * sn; Qp[base + 32] = q1 * sn + q2 * cs;
    float k1 = Kp[base], k2 = Kp[base + 32];
    Kp[base] = k1 * cs - k2 * sn; Kp[base + 32] = k1 * sn + k2 * cs;
}

__global__ void vtot_k(const float* __restrict__ Vp, float* __restrict__ VT) {
    int bh = blockIdx.x; int lane = threadIdx.x;         // grid 32, block 64
    int b = bh >> 4, h = bh & 15;
    float a0 = 0, a1 = 0, a2 = 0, a3 = 0;
    size_t base = ((size_t)b * CTXN) * DIMSN + h * 64 + lane;
    for (int t = 0; t < CTXN; t += 4) {
        a0 += Vp[base + (size_t)t * DIMSN];
        a1 += Vp[base + (size_t)(t + 1) * DIMSN];
        a2 += Vp[base + (size_t)(t + 2) * DIMSN];
        a3 += Vp[base + (size_t)(t + 3) * DIMSN];
    }
    VT[(bh << 6) + lane] = (a0 + a1) + (a2 + a3);
}

// one wave per (b, head, q-row). Faithful to qk*lower*sz then softmax over the
// FULL row (masked entries are exp(0), and contribute exp(-m)*v_j to output).
__global__ __launch_bounds__(64) void attn_k(
    const float* __restrict__ Qp, const float* __restrict__ Kp,
    const float* __restrict__ Vp, const float* __restrict__ VT,
    const float* __restrict__ factor, int layer, float* __restrict__ Op) {
    int t = blockIdx.x, h = blockIdx.y, b = blockIdx.z;
    int lane = threadIdx.x;
    __shared__ float qs[64];
    size_t rowbase = ((size_t)(b * CTXN + t)) * DIMSN + h * 64;
    qs[lane] = Qp[rowbase + lane];
    __syncthreads();
    float f = factor[layer];
    float zf = fminf(fmaxf(log1pf(expf(f)), 1e-5f), 0.1f);
    const int NC = 24;                                   // ceil(1500/64)
    float sc[NC];
    float mx = -3.0e38f;
#pragma unroll
    for (int c = 0; c < NC; c++) {
        int j = lane + (c << 6);
        float s = -3.0e38f;
        if (j <= t) {
            const float4* k4 = reinterpret_cast<const float4*>(
                Kp + ((size_t)(b * CTXN + j)) * DIMSN + h * 64);
            float dot = 0.f;
#pragma unroll
            for (int d = 0; d < 16; d++) {
                float4 kv = k4[d];
                dot += qs[4*d] * kv.x + qs[4*d+1] * kv.y + qs[4*d+2] * kv.z + qs[4*d+3] * kv.w;
            }
            float k0 = k4[0].x;
            float szv = (k0 == 0.0f) ? zf : 1.0f;
            s = dot * 0.125f * szv;                      // scale^2 = 1/8
            mx = fmaxf(mx, s);
        }
        sc[c] = s;
    }
#pragma unroll
    for (int off = 32; off > 0; off >>= 1) mx = fmaxf(mx, __shfl_xor(mx, off));
    int nmask = CTXN - 1 - t;
    float m = (nmask > 0) ? fmaxf(mx, 0.f) : mx;
    float ssum = 0.f;
#pragma unroll
    for (int c = 0; c < NC; c++) {
        int j = lane + (c << 6);
        float p = 0.f;
        if (j <= t) { p = expf(sc[c] - m); ssum += p; }
        sc[c] = p;
    }
#pragma unroll
    for (int off = 32; off > 0; off >>= 1) ssum += __shfl_xor(ssum, off);
    float em = expf(-m);
    float Z = ssum + (float)nmask * em;
    float o = 0.f, vpre = 0.f;
    for (int c = 0; c < NC; c++) {
        int jbase = c << 6;
        if (jbase > t) break;
        float p = sc[c];
        int lim = min(63, t - jbase);
        for (int l = 0; l <= lim; l++) {
            float pj = __shfl(p, l);
            float vv = Vp[((size_t)(b * CTXN + jbase + l)) * DIMSN + h * 64 + lane];
            o += pj * vv;
            vpre += vv;
        }
    }
    float vt = VT[((b * 16 + h) << 6) + lane];
    o = (o + em * (vt - vpre)) / Z;
    Op[rowbase + lane] = o;
}

// ---------------- launch ----------------
extern "C" void kernel_launch(void* const* d_in, const int* in_sizes, int n_in,
                              void* d_out, int out_size, void* d_ws, size_t ws_size,
                              hipStream_t stream) {
    const float* x      = (const float*)d_in[0];
    const float* wav    = (const float*)d_in[1];
    const float* se_w1  = (const float*)d_in[2];
    const float* se_b1  = (const float*)d_in[3];
    const float* se_w2  = (const float*)d_in[4];
    const float* se_b2  = (const float*)d_in[5];
    const float* se_w3  = (const float*)d_in[6];
    const float* se_b3  = (const float*)d_in[7];
    const float* se_w4  = (const float*)d_in[8];
    const float* se_b4  = (const float*)d_in[9];
    const float* se_fc1w = (const float*)d_in[10];
    const float* se_fc1b = (const float*)d_in[11];
    const float* se_fc2w = (const float*)d_in[12];
    const float* se_fc2b = (const float*)d_in[13];
    const float* se_w5  = (const float*)d_in[14];
    const float* se_b5  = (const float*)d_in[15];
    const float* we_w1  = (const float*)d_in[16];
    const float* we_b1  = (const float*)d_in[17];
    const float* we_w2  = (const float*)d_in[18];
    const float* we_b2  = (const float*)d_in[19];
    const float* qw     = (const float*)d_in[20];
    const float* qb     = (const float*)d_in[21];
    const float* kw     = (const float*)d_in[22];
    const float* vw     = (const float*)d_in[23];
    const float* vb     = (const float*)d_in[24];
    const float* ow     = (const float*)d_in[25];
    const float* ob     = (const float*)d_in[26];
    const float* factor = (const float*)d_in[27];
    const float* lna    = (const float*)d_in[28];
    const float* lnc    = (const float*)d_in[29];
    const float* m1w    = (const float*)d_in[30];
    const float* m1b    = (const float*)d_in[31];
    const float* m2w    = (const float*)d_in[32];
    const float* m2b    = (const float*)d_in[33];
    const float* lnE    = (const float*)d_in[34];
    const float* bsw    = (const float*)d_in[35];

    float* ws = (float*)d_ws;
    // compact layout (floats):
    float* H   = ws;                 // 3,072,000
    float* H1  = ws + 3072000;       // 3,072,000
    float* U   = ws + 6144000;       // 3,072,000
    float* Qb_ = ws + 9216000;       // 3,072,000
    float* Kb_ = ws + 12288000;      // 3,072,000
    float* Vb_ = ws + 15360000;      // 3,072,000 (+ tail to 21,504,000 for M1)
    float* M1  = ws + 9216000;       // 12,288,000 (aliases Q/K/V + tail; dead by then)
    float* SM  = ws + 21504000;      // small: Y0(2048) Y1(128) Y2(2048) VT(2048)
    float* Y0 = SM, *Y1 = SM + 2048, *Y2 = SM + 2176, *VT = SM + 4224;
    // stem-phase aliases (dead before transformer uses them)
    float* SPA = Qb_;
    float* SPB = Kb_;
    float* P   = Vb_;

    const size_t NEED = (size_t)(21504000 + 8192) * sizeof(float);   // ~82 MiB
    if (ws_size < NEED) {
        // diagnostic: report actual ws_size via the absmax error
        sentinel_k<<<1, 1, 0, stream>>>((float*)d_out, (float)ws_size);
        return;
    }

    dim3 cgrid(24, 16, 2);
    // spectrogram stem
    conv1d_t<3, 66, 1><<<cgrid, 256, 0, stream>>>(x,   se_w1, se_b1, SPA, 128,  1500, 1500, 1, 1, 1);
    conv1d_t<3, 68, 0><<<cgrid, 256, 0, stream>>>(SPA, se_w2, se_b2, SPB, 1024, 1500, 1500, 1, 2, 2);
    dwconv_k<<<12000, 256, 0, stream>>>(SPB, se_w3, se_b3, SPA);
    conv1d_t<1, 64, 0><<<cgrid, 256, 0, stream>>>(SPA, se_w4, se_b4, SPB, 1024, 1500, 1500, 1, 1, 0);
    se_mean_k<<<2048, 64, 0, stream>>>(SPB, Y0);
    se_fc1_k<<<1, 128, 0, stream>>>(Y0, se_fc1w, se_fc1b, Y1);
    se_fc2_k<<<8, 256, 0, stream>>>(Y1, se_fc2w, se_fc2b, Y2);
    se_scale_k<<<12000, 256, 0, stream>>>(SPB, Y2, SPA);
    conv1d_t<3, 66, 0><<<cgrid, 256, 0, stream>>>(SPA, se_w5, se_b5, SPB, 1024, 1500, 1500, 1, 1, 1);
    // fused waveform stem -> P [B, CTX, D] (pooled /10)
    we_fused_k<<<dim3(188, 16, 2), 256, 0, stream>>>(wav, we_w1, we_b1, we_w2, we_b2, P);
    // blend + sinusoids -> H [B,CTX,D]
    blend_k<<<12000, 256, 0, stream>>>(SPB, P, bsw, H);

    for (int L = 0; L < 4; L++) {
        rmsnorm_k<<<3000, 256, 0, stream>>>(H, lna + L * 1024, U);
        gemm_nt_k<<<dim3(16, 47), 256, 0, stream>>>(U, qw + (size_t)L * 1048576, qb + L * 1024,
                                                    nullptr, nullptr, Qb_, 3000, 1024, 1024, 0);
        gemm_nt_k<<<dim3(16, 47), 256, 0, stream>>>(U, kw + (size_t)L * 1048576, nullptr,
                                                    nullptr, nullptr, Kb_, 3000, 1024, 1024, 0);
        gemm_nt_k<<<dim3(16, 47), 256, 0, stream>>>(U, vw + (size_t)L * 1048576, vb + L * 1024,
                                                    nullptr, nullptr, Vb_, 3000, 1024, 1024, 0);
        rope_k<<<6000, 256, 0, stream>>>(Qb_, Kb_);
        vtot_k<<<32, 64, 0, stream>>>(Vb_, VT);
        attn_k<<<dim3(1500, 16, 2), 64, 0, stream>>>(Qb_, Kb_, Vb_, VT, factor, L, U);
        // h1 = h_in + attn_out @ ow + ob   (U dead as rms buffer; holds attn out)
        gemm_nt_k<<<dim3(16, 47), 256, 0, stream>>>(U, ow + (size_t)L * 1048576, ob + L * 1024,
                                                    H, nullptr, H1, 3000, 1024, 1024, 0);
        rmsnorm_k<<<3000, 256, 0, stream>>>(H1, lnc + L * 1024, U);
        gemm_nt_k<<<dim3(64, 47), 256, 0, stream>>>(U, m1w + (size_t)L * 4194304, m1b + L * 4096,
                                                    nullptr, nullptr, M1, 3000, 4096, 1024, 1);
        // h = mlp + h1 + h_in  (= 2*h_in + attn + mlp)
        gemm_nt_k<<<dim3(16, 47), 256, 0, stream>>>(M1, m2w + (size_t)L * 4194304, m2b + L * 1024,
                                                    H1, H, H, 3000, 1024, 4096, 0);
    }
    rmsnorm_k<<<3000, 256, 0, stream>>>(H, lnE, (float*)d_out);
}

// Round 3
// 14501.074 us; speedup vs baseline: 1.5513x; 1.5513x over previous
//
#include <hip/hip_runtime.h>
#include <math.h>

// B=2, MELS=128, CTX=1500, DIMS=1024, HEAD=16, HD=64, LAYER=4, NSAMP=150000
#define CTXN 1500
#define DIMSN 1024

typedef __attribute__((ext_vector_type(8))) short short8b;
typedef __attribute__((ext_vector_type(4))) float f32x4;

__device__ __forceinline__ float gelu_f(float x) {
    float x3 = x * x * x;
    float t = tanhf(0.7978845608028654f * (x + 0.044715f * x3));
    return 0.5f * x * (1.0f + t);
}

__device__ __forceinline__ unsigned short f2bf(float f) {
    unsigned u = __builtin_bit_cast(unsigned, f);
    unsigned r = (u + 0x7FFFu + ((u >> 16) & 1u)) >> 16;
    return (unsigned short)r;
}
__device__ __forceinline__ float bf2f(unsigned short s) {
    return __builtin_bit_cast(float, ((unsigned)s) << 16);
}

__device__ __forceinline__ void gld16(const unsigned short* g, unsigned short* l) {
    __builtin_amdgcn_global_load_lds(
        (const __attribute__((address_space(1))) unsigned int*)g,
        (__attribute__((address_space(3))) unsigned int*)l, 16, 0, 0);
}

__global__ void sentinel_k(float* out, float v) { out[0] = v; }

// ---------------- tiled implicit-GEMM conv1d (fp32, spectro stem) ----------------
template<int KS, int SPAN, int ACT>
__global__ __launch_bounds__(256) void conv1d_t(
    const float* __restrict__ in, const float* __restrict__ wt,
    const float* __restrict__ bias, float* __restrict__ out,
    int IC, int Tin, int Tout, int stride, int dil, int pad) {
    __shared__ float Ws[16][KS][65];
    __shared__ float Gs[16][SPAN];
    int tid = threadIdx.x;
    int t0 = blockIdx.x * 64;
    int oc0 = blockIdx.y * 64;
    int b = blockIdx.z;
    int tx = tid & 15, ty = tid >> 4;
    float acc[4][4] = {{0.f}};
    int tbase = t0 * stride - pad;
    for (int ic0 = 0; ic0 < IC; ic0 += 16) {
        for (int idx = tid; idx < 64 * 16 * KS; idx += 256) {
            int o = idx / (16 * KS); int r = idx - o * 16 * KS;
            int i = r / KS; int j = r - i * KS;
            Ws[i][j][o] = wt[(size_t)(oc0 + o) * IC * KS + (size_t)(ic0 + i) * KS + j];
        }
        for (int idx = tid; idx < 16 * SPAN; idx += 256) {
            int i = idx / SPAN; int s = idx - i * SPAN;
            int ti = tbase + s;
            Gs[i][s] = (ti >= 0 && ti < Tin) ? in[((size_t)b * IC + ic0 + i) * Tin + ti] : 0.f;
        }
        __syncthreads();
#pragma unroll
        for (int i = 0; i < 16; i++) {
            float wv[4][KS];
#pragma unroll
            for (int o = 0; o < 4; o++)
#pragma unroll
                for (int j = 0; j < KS; j++) wv[o][j] = Ws[i][j][ty * 4 + o];
#pragma unroll
            for (int tj = 0; tj < 4; tj++) {
                int gb = (tx * 4 + tj) * stride;
#pragma unroll
                for (int j = 0; j < KS; j++) {
                    float g = Gs[i][gb + j * dil];
#pragma unroll
                    for (int o = 0; o < 4; o++) acc[o][tj] += wv[o][j] * g;
                }
            }
        }
        __syncthreads();
    }
#pragma unroll
    for (int o = 0; o < 4; o++) {
        int oc = oc0 + ty * 4 + o;
        float bz = bias[oc];
#pragma unroll
        for (int tj = 0; tj < 4; tj++) {
            int t = t0 + tx * 4 + tj;
            if (t < Tout) {
                float v = acc[o][tj] + bz;
                if (ACT == 1) v = gelu_f(v);
                out[((size_t)b * DIMSN + oc) * Tout + t] = v;
            }
        }
    }
}

// ------------- waveform stem pipeline -------------
// wcvt: wb2[j][oc][ic] = bf16(we_w2[oc][ic][j])
__global__ void wcvt_k(const float* __restrict__ w2, unsigned short* __restrict__ wb2) {
    int idx = blockIdx.x * 256 + threadIdx.x;           // 5*1024*1024
    int j = idx >> 20;
    int rest = idx & 1048575;
    int oc = rest >> 10, ic = rest & 1023;
    wb2[idx] = f2bf(w2[((size_t)oc * 1024 + ic) * 5 + j]);
}

// conv1 (k=11, s=5, p=5) + gelu -> G1e[b][r][ic] bf16 (token-major), rows 3768
__global__ __launch_bounds__(256) void we1_bf_k(
    const float* __restrict__ wav, const float* __restrict__ w1,
    const float* __restrict__ b1, unsigned short* __restrict__ G1e, int t1base) {
    int idx = blockIdx.x * 256 + threadIdx.x;           // 2*3768*1024
    if (idx >= 2 * 3768 * 1024) return;
    int ic = idx & 1023;
    int rest = idx >> 10;
    int r = rest % 3768;
    int b = rest / 3768;
    int t1 = t1base + r;
    float g = 0.f;
    if (t1 >= 0 && t1 < 30000) {
        float acc = b1[ic];
        const float* wv = wav + (size_t)b * 150000;
        int base = t1 * 5 - 5;
#pragma unroll
        for (int j = 0; j < 11; j++) {
            int ti = base + j;
            if (ti >= 0 && ti < 150000) acc += w1[ic * 11 + j] * wv[ti];
        }
        g = gelu_f(acc);
    }
    G1e[idx] = f2bf(g);
}

// conv2 (k=5, s=2, p=2) via MFMA implicit GEMM; gelu epilogue -> G2e[b][tt][oc] bf16
// grid (15, 8, 2), 256 threads, tile 128(t2) x 128(oc)
__global__ __launch_bounds__(256) void conv2_mfma_k(
    const unsigned short* __restrict__ G1e, const unsigned short* __restrict__ wb2,
    const float* __restrict__ b2, unsigned short* __restrict__ G2e, int len) {
    __shared__ unsigned short Al[4096];
    __shared__ unsigned short Wl[4096];
    int tid = threadIdx.x;
    int tt0 = blockIdx.x * 128;
    int oc0 = blockIdx.y * 128;
    int b = blockIdx.z;
    int lane = tid & 63, w = tid >> 6;
    int wm = (w >> 1) * 64, wn = (w & 1) * 64;
    f32x4 z = {0.f, 0.f, 0.f, 0.f};
    f32x4 acc[4][4];
#pragma unroll
    for (int i = 0; i < 4; i++)
#pragma unroll
        for (int j = 0; j < 4; j++) acc[i][j] = z;
    int c1 = tid, c2 = tid + 256;
    int kg1 = c1 >> 7, m1 = c1 & 127, kg2 = c2 >> 7, m2 = c2 & 127;
    int tA1 = tt0 + m1; if (tA1 > len - 1) tA1 = len - 1;
    int tA2 = tt0 + m2; if (tA2 > len - 1) tA2 = len - 1;
    for (int j = 0; j < 5; j++) {
        for (int ic0 = 0; ic0 < 1024; ic0 += 32) {
            int r1 = 2 * tA1 + j, r2 = 2 * tA2 + j;
            gld16(G1e + ((size_t)(b * 3768 + r1) * 1024 + ic0 + kg1 * 8), &Al[c1 * 8]);
            gld16(G1e + ((size_t)(b * 3768 + r2) * 1024 + ic0 + kg2 * 8), &Al[c2 * 8]);
            gld16(wb2 + ((size_t)((j << 10) + oc0 + m1) * 1024 + ic0 + kg1 * 8), &Wl[c1 * 8]);
            gld16(wb2 + ((size_t)((j << 10) + oc0 + m2) * 1024 + ic0 + kg2 * 8), &Wl[c2 * 8]);
            __syncthreads();
            const unsigned short* Ab = &Al[(((lane >> 4) * 128) + wm + (lane & 15)) * 8];
            const unsigned short* Wb = &Wl[(((lane >> 4) * 128) + wn + (lane & 15)) * 8];
            short8b af[4], bfv[4];
#pragma unroll
            for (int i = 0; i < 4; i++) af[i] = *(const short8b*)(Ab + i * 128);
#pragma unroll
            for (int i = 0; i < 4; i++) bfv[i] = *(const short8b*)(Wb + i * 128);
#pragma unroll
            for (int mt = 0; mt < 4; mt++)
#pragma unroll
                for (int nt = 0; nt < 4; nt++)
                    acc[mt][nt] = __builtin_amdgcn_mfma_f32_16x16x32_bf16(
                        af[mt], bfv[nt], acc[mt][nt], 0, 0, 0);
            __syncthreads();
        }
    }
    int r4 = (lane >> 4) * 4, cn = lane & 15;
#pragma unroll
    for (int nt = 0; nt < 4; nt++) {
        int oc = oc0 + wn + nt * 16 + cn;
        float bz = b2[oc];
#pragma unroll
        for (int mt = 0; mt < 4; mt++)
#pragma unroll
            for (int rr = 0; rr < 4; rr++) {
                int tt = tt0 + wm + mt * 16 + r4 + rr;
                if (tt < len)
                    G2e[((size_t)b * 1880 + tt) * 1024 + oc] = f2bf(gelu_f(acc[mt][nt][rr] + bz));
            }
    }
}

// mean over 10 t2 -> P[b][ct][oc] fp32
__global__ void pool_k(const unsigned short* __restrict__ G2e, float* __restrict__ P,
                       int clen, int ct0) {
    int idx = blockIdx.x * 256 + threadIdx.x;           // 2*clen*1024
    int oc = idx & 1023;
    int rest = idx >> 10;
    int cl = rest % clen;
    int b = rest / clen;
    if (b >= 2) return;
    const unsigned short* g = G2e + ((size_t)b * 1880 + cl * 10) * 1024 + oc;
    float s = 0.f;
#pragma unroll
    for (int i = 0; i < 10; i++) s += bf2f(g[i * 1024]);
    P[((size_t)(b * CTXN) + ct0 + cl) * 1024 + oc] = s * 0.1f;
}

// ---------------- MFMA GEMM: C[m,n] = res1+res2+act(bias + A·W[n,:]) ----------------
// A [M,K] bf16 global, W [N,K] fp32 global (reg-staged to bf16).
// 128x128 tile, 4 waves, BK=32.
__global__ __launch_bounds__(256) void gemm_mfma_k(
    const unsigned short* __restrict__ A, const float* __restrict__ W,
    const float* __restrict__ bias, const float* __restrict__ res1,
    const float* __restrict__ res2, void* __restrict__ C,
    int M, int N, int K, int act, int outbf) {
    __shared__ unsigned short Al[4096];
    __shared__ unsigned short Wl[4096];
    int tid = threadIdx.x;
    int n0 = blockIdx.x * 128, m0 = blockIdx.y * 128;
    int lane = tid & 63, w = tid >> 6;
    int wm = (w >> 1) * 64, wn = (w & 1) * 64;
    f32x4 z = {0.f, 0.f, 0.f, 0.f};
    f32x4 acc[4][4];
#pragma unroll
    for (int i = 0; i < 4; i++)
#pragma unroll
        for (int j = 0; j < 4; j++) acc[i][j] = z;
    int c1 = tid, c2 = tid + 256;
    int kg1 = c1 >> 7, m1 = c1 & 127, kg2 = c2 >> 7, m2 = c2 & 127;
    int ra1 = m0 + m1; if (ra1 > M - 1) ra1 = M - 1;
    int ra2 = m0 + m2; if (ra2 > M - 1) ra2 = M - 1;
    for (int k0 = 0; k0 < K; k0 += 32) {
        gld16(A + (size_t)ra1 * K + k0 + kg1 * 8, &Al[c1 * 8]);
        gld16(A + (size_t)ra2 * K + k0 + kg2 * 8, &Al[c2 * 8]);
        {
            const float* wp = W + (size_t)(n0 + m1) * K + k0 + kg1 * 8;
            float4 fa = *(const float4*)wp;
            float4 fb = *(const float4*)(wp + 4);
            short8b v;
            v[0] = (short)f2bf(fa.x); v[1] = (short)f2bf(fa.y);
            v[2] = (short)f2bf(fa.z); v[3] = (short)f2bf(fa.w);
            v[4] = (short)f2bf(fb.x); v[5] = (short)f2bf(fb.y);
            v[6] = (short)f2bf(fb.z); v[7] = (short)f2bf(fb.w);
            *(short8b*)&Wl[c1 * 8] = v;
            wp = W + (size_t)(n0 + m2) * K + k0 + kg2 * 8;
            fa = *(const float4*)wp;
            fb = *(const float4*)(wp + 4);
            v[0] = (short)f2bf(fa.x); v[1] = (short)f2bf(fa.y);
            v[2] = (short)f2bf(fa.z); v[3] = (short)f2bf(fa.w);
            v[4] = (short)f2bf(fb.x); v[5] = (short)f2bf(fb.y);
            v[6] = (short)f2bf(fb.z); v[7] = (short)f2bf(fb.w);
            *(short8b*)&Wl[c2 * 8] = v;
        }
        __syncthreads();
        const unsigned short* Ab = &Al[(((lane >> 4) * 128) + wm + (lane & 15)) * 8];
        const unsigned short* Wb = &Wl[(((lane >> 4) * 128) + wn + (lane & 15)) * 8];
        short8b af[4], bfv[4];
#pragma unroll
        for (int i = 0; i < 4; i++) af[i] = *(const short8b*)(Ab + i * 128);
#pragma unroll
        for (int i = 0; i < 4; i++) bfv[i] = *(const short8b*)(Wb + i * 128);
#pragma unroll
        for (int mt = 0; mt < 4; mt++)
#pragma unroll
            for (int nt = 0; nt < 4; nt++)
                acc[mt][nt] = __builtin_amdgcn_mfma_f32_16x16x32_bf16(
                    af[mt], bfv[nt], acc[mt][nt], 0, 0, 0);
        __syncthreads();
    }
    int r4 = (lane >> 4) * 4, cn = lane & 15;
#pragma unroll
    for (int nt = 0; nt < 4; nt++) {
        int n = n0 + wn + nt * 16 + cn;
        float bz = bias ? bias[n] : 0.f;
#pragma unroll
        for (int mt = 0; mt < 4; mt++)
#pragma unroll
            for (int rr = 0; rr < 4; rr++) {
                int m = m0 + wm + mt * 16 + r4 + rr;
                if (m >= M) continue;
                float v = acc[mt][nt][rr] + bz;
                if (act) v = fmaxf(v, 0.f);
                size_t off = (size_t)m * N + n;
                if (res1) v += res1[off];
                if (res2) v += res2[off];
                if (outbf) ((unsigned short*)C)[off] = f2bf(v);
                else ((float*)C)[off] = v;
            }
    }
}

// ---------------- small elementwise / stem kernels ----------------
__global__ void dwconv_k(const float* __restrict__ in, const float* __restrict__ w3,
                         const float* __restrict__ b3, float* __restrict__ out) {
    int idx = blockIdx.x * 256 + threadIdx.x;           // 2*1024*1500
    int t = idx % CTXN;
    int bc = idx / CTXN;
    int c = bc & 1023;
    float acc = b3[c];
#pragma unroll
    for (int j = 0; j < 3; j++) {
        int ti = t - 1 + j;
        if (ti >= 0 && ti < CTXN) acc += w3[c * 3 + j] * in[(size_t)bc * CTXN + ti];
    }
    out[idx] = acc;
}

__global__ void se_mean_k(const float* __restrict__ in, float* __restrict__ y0) {
    int bc = blockIdx.x; int lane = threadIdx.x;        // 64
    float acc = 0.f;
    for (int t = lane; t < CTXN; t += 64) acc += in[(size_t)bc * CTXN + t];
#pragma unroll
    for (int off = 32; off > 0; off >>= 1) acc += __shfl_xor(acc, off);
    if (lane == 0) y0[bc] = acc / 1500.f;
}

__global__ void se_fc1_k(const float* __restrict__ y0, const float* __restrict__ w,
                         const float* __restrict__ b, float* __restrict__ y1) {
    int tid = threadIdx.x;                               // 128 = 2b x 64n
    int bb = tid >> 6, n = tid & 63;
    float acc = b[n];
    for (int k = 0; k < 1024; k++) acc += y0[bb * 1024 + k] * w[n * 1024 + k];
    y1[bb * 64 + n] = fmaxf(acc, 0.f);
}

__global__ void se_fc2_k(const float* __restrict__ y1, const float* __restrict__ w,
                         const float* __restrict__ b, float* __restrict__ y2) {
    int idx = blockIdx.x * 256 + threadIdx.x;            // 2048
    int bb = idx >> 10, c = idx & 1023;
    float acc = b[c];
#pragma unroll
    for (int k = 0; k < 64; k++) acc += y1[bb * 64 + k] * w[c * 64 + k];
    y2[idx] = 1.f / (1.f + expf(-acc));
}

__global__ void se_scale_k(const float* __restrict__ in, const float* __restrict__ y2,
                           float* __restrict__ out) {
    int idx = blockIdx.x * 256 + threadIdx.x;            // 2*1024*1500
    int bc = idx / CTXN;
    out[idx] = gelu_f(in[idx] * y2[bc]);
}

// h[b,t,d] = blend*xs[b,d,t] + (1-blend)*P[b,t,d] + sinusoid(t,d)
__global__ void blend_k(const float* __restrict__ H6, const float* __restrict__ P,
                        const float* __restrict__ bsw, float* __restrict__ Hs) {
    int idx = blockIdx.x * 256 + threadIdx.x;            // 2*1500*1024
    int d = idx & 1023;
    int rest = idx >> 10;                                // b*1500 + t
    int t = rest % CTXN;
    int b = rest / CTXN;
    float xs = H6[((size_t)b * DIMSN + d) * CTXN + t];
    float wsv = P[idx];
    float bl = 1.f / (1.f + expf(-bsw[0]));
    float pos;
    if (d < 512) {
        float inv = expf(-0.018024149455921103f * (float)d);
        pos = sinf((float)t * inv);
    } else {
        float inv = expf(-0.018024149455921103f * (float)(d - 512));
        pos = cosf((float)t * inv);
    }
    Hs[idx] = bl * xs + (1.f - bl) * wsv + pos;
}

// rmsnorm; OB=1 -> bf16 out, else fp32
template<int OB>
__global__ __launch_bounds__(256) void rmsnorm_k(const float* __restrict__ X,
    const float* __restrict__ Wt, void* __restrict__ Y) {
    int row = blockIdx.x; int tid = threadIdx.x;
    const float* x = X + (size_t)row * DIMSN;
    float ss = 0.f;
    for (int d = tid; d < DIMSN; d += 256) { float v = x[d]; ss += v * v; }
    __shared__ float red[256];
    red[tid] = ss; __syncthreads();
    for (int s = 128; s > 0; s >>= 1) { if (tid < s) red[tid] += red[tid + s]; __syncthreads(); }
    float r = rsqrtf(red[0] / (float)DIMSN + 1e-8f);
    for (int d = tid; d < DIMSN; d += 256) {
        float v = x[d] * r * Wt[d];
        if (OB) ((unsigned short*)Y)[(size_t)row * DIMSN + d] = f2bf(v);
        else ((float*)Y)[(size_t)row * DIMSN + d] = v;
    }
}

// in-place rotate-half RoPE on Q and K
__global__ void rope_k(float* __restrict__ Qp, float* __restrict__ Kp) {
    int idx = blockIdx.x * 256 + threadIdx.x;            // 2*1500*16*32
    int d = idx & 31;
    int h = (idx >> 5) & 15;
    int row = idx >> 9;
    int t = row % CTXN;
    float inv = 1.0f / powf(10000.0f, (float)d / 32.0f);
    float fr = (float)t * inv;
    float sn, cs;
    sincosf(fr, &sn, &cs);
    size_t base = (size_t)row * DIMSN + h * 64 + d;
    float q1 = Qp[base], q2 = Qp[base + 32];
    Qp[base] = q1 * cs - q2 * sn; Qp[base + 32] = q1 * sn + q2 * cs;
    float k1 = Kp[base], k2 = Kp[base + 32];
    Kp[base] = k1 * cs - k2 * sn; Kp[base + 32] = k1 * sn + k2 * cs;
}

__global__ void vtot_k(const float* __restrict__ Vp, float* __restrict__ VT) {
    int bh = blockIdx.x; int lane = threadIdx.x;         // grid 32, block 64
    int b = bh >> 4, h = bh & 15;
    float a0 = 0, a1 = 0, a2 = 0, a3 = 0;
    size_t base = ((size_t)b * CTXN) * DIMSN + h * 64 + lane;
    for (int t = 0; t < CTXN; t += 4) {
        a0 += Vp[base + (size_t)t * DIMSN];
        a1 += Vp[base + (size_t)(t + 1) * DIMSN];
        a2 += Vp[base + (size_t)(t + 2) * DIMSN];
        a3 += Vp[base + (size_t)(t + 3) * DIMSN];
    }
    VT[(bh << 6) + lane] = (a0 + a1) + (a2 + a3);
}

// one wave per (b, head, q-row); faithful mult-mask softmax; bf16 output
__global__ __launch_bounds__(64) void attn_k(
    const float* __restrict__ Qp, const float* __restrict__ Kp,
    const float* __restrict__ Vp, const float* __restrict__ VT,
    const float* __restrict__ factor, int layer, unsigned short* __restrict__ Op) {
    int t = blockIdx.x, h = blockIdx.y, b = blockIdx.z;
    int lane = threadIdx.x;
    __shared__ float qs[64];
    size_t rowbase = ((size_t)(b * CTXN + t)) * DIMSN + h * 64;
    qs[lane] = Qp[rowbase + lane];
    __syncthreads();
    float f = factor[layer];
    float zf = fminf(fmaxf(log1pf(expf(f)), 1e-5f), 0.1f);
    const int NC = 24;
    float sc[NC];
    float mx = -3.0e38f;
#pragma unroll
    for (int c = 0; c < NC; c++) {
        int j = lane + (c << 6);
        float s = -3.0e38f;
        if (j <= t) {
            const float4* k4 = reinterpret_cast<const float4*>(
                Kp + ((size_t)(b * CTXN + j)) * DIMSN + h * 64);
            float dot = 0.f;
#pragma unroll
            for (int d = 0; d < 16; d++) {
                float4 kv = k4[d];
                dot += qs[4*d] * kv.x + qs[4*d+1] * kv.y + qs[4*d+2] * kv.z + qs[4*d+3] * kv.w;
            }
            float k0 = k4[0].x;
            float szv = (k0 == 0.0f) ? zf : 1.0f;
            s = dot * 0.125f * szv;
            mx = fmaxf(mx, s);
        }
        sc[c] = s;
    }
#pragma unroll
    for (int off = 32; off > 0; off >>= 1) mx = fmaxf(mx, __shfl_xor(mx, off));
    int nmask = CTXN - 1 - t;
    float m = (nmask > 0) ? fmaxf(mx, 0.f) : mx;
    float ssum = 0.f;
#pragma unroll
    for (int c = 0; c < NC; c++) {
        int j = lane + (c << 6);
        float p = 0.f;
        if (j <= t) { p = expf(sc[c] - m); ssum += p; }
        sc[c] = p;
    }
#pragma unroll
    for (int off = 32; off > 0; off >>= 1) ssum += __shfl_xor(ssum, off);
    float em = expf(-m);
    float Z = ssum + (float)nmask * em;
    float o = 0.f, vpre = 0.f;
    for (int c = 0; c < NC; c++) {
        int jbase = c << 6;
        if (jbase > t) break;
        float p = sc[c];
        int lim = min(63, t - jbase);
        for (int l = 0; l <= lim; l++) {
            float pj = __shfl(p, l);
            float vv = Vp[((size_t)(b * CTXN + jbase + l)) * DIMSN + h * 64 + lane];
            o += pj * vv;
            vpre += vv;
        }
    }
    float vt = VT[((b * 16 + h) << 6) + lane];
    o = (o + em * (vt - vpre)) / Z;
    Op[rowbase + lane] = f2bf(o);
}

// ---------------- launch ----------------
extern "C" void kernel_launch(void* const* d_in, const int* in_sizes, int n_in,
                              void* d_out, int out_size, void* d_ws, size_t ws_size,
                              hipStream_t stream) {
    const float* x      = (const float*)d_in[0];
    const float* wav    = (const float*)d_in[1];
    const float* se_w1  = (const float*)d_in[2];
    const float* se_b1  = (const float*)d_in[3];
    const float* se_w2  = (const float*)d_in[4];
    const float* se_b2  = (const float*)d_in[5];
    const float* se_w3  = (const float*)d_in[6];
    const float* se_b3  = (const float*)d_in[7];
    const float* se_w4  = (const float*)d_in[8];
    const float* se_b4  = (const float*)d_in[9];
    const float* se_fc1w = (const float*)d_in[10];
    const float* se_fc1b = (const float*)d_in[11];
    const float* se_fc2w = (const float*)d_in[12];
    const float* se_fc2b = (const float*)d_in[13];
    const float* se_w5  = (const float*)d_in[14];
    const float* se_b5  = (const float*)d_in[15];
    const float* we_w1  = (const float*)d_in[16];
    const float* we_b1  = (const float*)d_in[17];
    const float* we_w2  = (const float*)d_in[18];
    const float* we_b2  = (const float*)d_in[19];
    const float* qw     = (const float*)d_in[20];
    const float* qb     = (const float*)d_in[21];
    const float* kw     = (const float*)d_in[22];
    const float* vw     = (const float*)d_in[23];
    const float* vb     = (const float*)d_in[24];
    const float* ow     = (const float*)d_in[25];
    const float* ob     = (const float*)d_in[26];
    const float* factor = (const float*)d_in[27];
    const float* lna    = (const float*)d_in[28];
    const float* lnc    = (const float*)d_in[29];
    const float* m1w    = (const float*)d_in[30];
    const float* m1b    = (const float*)d_in[31];
    const float* m2w    = (const float*)d_in[32];
    const float* m2b    = (const float*)d_in[33];
    const float* lnE    = (const float*)d_in[34];
    const float* bsw    = (const float*)d_in[35];

    float* ws = (float*)d_ws;
    // float-unit offsets
    float* H   = ws;                       // 3,072,000 f
    float* H1  = ws + 3072000;             // 3,072,000 f
    unsigned short* Ubf = (unsigned short*)(ws + 6144000);   // 3,072,000 bf16
    float* Qb_ = ws + 7680000;             // 3,072,000 f
    float* Kb_ = ws + 10752000;            // 3,072,000 f
    float* Vb_ = ws + 13824000;            // 3,072,000 f
    unsigned short* G1e = (unsigned short*)(ws + 16896000);  // 2*3768*1024 bf16
    float* SM  = ws + 20754432;
    float* Y0 = SM, *Y1 = SM + 2048, *Y2 = SM + 2176, *VT = SM + 4224;
    // aliases
    unsigned short* M1bf = (unsigned short*)Qb_;   // 3000*4096 bf16 over Qb+Kb
    unsigned short* wb2  = (unsigned short*)Qb_;   // 5*1024*1024 bf16 (stem phase)
    float* SPA = Qb_;
    float* SPB = Kb_;
    float* P   = Vb_;
    unsigned short* G2e = (unsigned short*)H;      // 2*1880*1024 bf16 (stem phase)

    const size_t NEED = (size_t)(20754432 + 8192) * sizeof(float);   // ~83 MB
    if (ws_size < NEED) {
        sentinel_k<<<1, 1, 0, stream>>>((float*)d_out, (float)ws_size);
        return;
    }

    // ---- waveform stem (8 time-chunks of 1880 t2) ----
    wcvt_k<<<20480, 256, 0, stream>>>(we_w2, wb2);
    for (int e = 0; e < 8; e++) {
        int len = (e == 7) ? 1840 : 1880;
        int t1base = 3760 * e - 2;
        we1_bf_k<<<30144, 256, 0, stream>>>(wav, we_w1, we_b1, G1e, t1base);
        conv2_mfma_k<<<dim3(15, 8, 2), 256, 0, stream>>>(G1e, wb2, we_b2, G2e, len);
        int clen = len / 10;
        pool_k<<<(2 * clen * 1024) / 256, 256, 0, stream>>>(G2e, P, clen, e * 188);
    }
    // ---- spectrogram stem ----
    dim3 cgrid(24, 16, 2);
    conv1d_t<3, 66, 1><<<cgrid, 256, 0, stream>>>(x,   se_w1, se_b1, SPA, 128,  1500, 1500, 1, 1, 1);
    conv1d_t<3, 68, 0><<<cgrid, 256, 0, stream>>>(SPA, se_w2, se_b2, SPB, 1024, 1500, 1500, 1, 2, 2);
    dwconv_k<<<12000, 256, 0, stream>>>(SPB, se_w3, se_b3, SPA);
    conv1d_t<1, 64, 0><<<cgrid, 256, 0, stream>>>(SPA, se_w4, se_b4, SPB, 1024, 1500, 1500, 1, 1, 0);
    se_mean_k<<<2048, 64, 0, stream>>>(SPB, Y0);
    se_fc1_k<<<1, 128, 0, stream>>>(Y0, se_fc1w, se_fc1b, Y1);
    se_fc2_k<<<8, 256, 0, stream>>>(Y1, se_fc2w, se_fc2b, Y2);
    se_scale_k<<<12000, 256, 0, stream>>>(SPB, Y2, SPA);
    conv1d_t<3, 66, 0><<<cgrid, 256, 0, stream>>>(SPA, se_w5, se_b5, SPB, 1024, 1500, 1500, 1, 1, 1);
    // blend + sinusoids -> H [B,CTX,D]
    blend_k<<<12000, 256, 0, stream>>>(SPB, P, bsw, H);

    // ---- transformer ----
    for (int L = 0; L < 4; L++) {
        rmsnorm_k<1><<<3000, 256, 0, stream>>>(H, lna + L * 1024, Ubf);
        gemm_mfma_k<<<dim3(8, 24), 256, 0, stream>>>(Ubf, qw + (size_t)L * 1048576, qb + L * 1024,
                                                     nullptr, nullptr, Qb_, 3000, 1024, 1024, 0, 0);
        gemm_mfma_k<<<dim3(8, 24), 256, 0, stream>>>(Ubf, kw + (size_t)L * 1048576, nullptr,
                                                     nullptr, nullptr, Kb_, 3000, 1024, 1024, 0, 0);
        gemm_mfma_k<<<dim3(8, 24), 256, 0, stream>>>(Ubf, vw + (size_t)L * 1048576, vb + L * 1024,
                                                     nullptr, nullptr, Vb_, 3000, 1024, 1024, 0, 0);
        rope_k<<<6000, 256, 0, stream>>>(Qb_, Kb_);
        vtot_k<<<32, 64, 0, stream>>>(Vb_, VT);
        attn_k<<<dim3(1500, 16, 2), 64, 0, stream>>>(Qb_, Kb_, Vb_, VT, factor, L, Ubf);
        gemm_mfma_k<<<dim3(8, 24), 256, 0, stream>>>(Ubf, ow + (size_t)L * 1048576, ob + L * 1024,
                                                     H, nullptr, H1, 3000, 1024, 1024, 0, 0);
        rmsnorm_k<1><<<3000, 256, 0, stream>>>(H1, lnc + L * 1024, Ubf);
        gemm_mfma_k<<<dim3(32, 24), 256, 0, stream>>>(Ubf, m1w + (size_t)L * 4194304, m1b + L * 4096,
                                                      nullptr, nullptr, M1bf, 3000, 4096, 1024, 1, 1);
        gemm_mfma_k<<<dim3(8, 24), 256, 0, stream>>>(M1bf, m2w + (size_t)L * 4194304, m2b + L * 1024,
                                                     H1, H, H, 3000, 1024, 4096, 0, 0);
    }
    rmsnorm_k<0><<<3000, 256, 0, stream>>>(H, lnE, (float*)d_out);
}

// Round 4
// 7533.221 us; speedup vs baseline: 2.9862x; 1.9250x over previous
//
#include <hip/hip_runtime.h>
#include <math.h>

// B=2, MELS=128, CTX=1500, DIMS=1024, HEAD=16, HD=64, LAYER=4, NSAMP=150000
#define CTXN 1500
#define DIMSN 1024

typedef __attribute__((ext_vector_type(8))) short short8b;
typedef __attribute__((ext_vector_type(4))) float f32x4;

__device__ __forceinline__ float gelu_f(float x) {
    float x3 = x * x * x;
    float t = tanhf(0.7978845608028654f * (x + 0.044715f * x3));
    return 0.5f * x * (1.0f + t);
}

__device__ __forceinline__ unsigned short f2bf(float f) {
    unsigned u = __builtin_bit_cast(unsigned, f);
    unsigned r = (u + 0x7FFFu + ((u >> 16) & 1u)) >> 16;
    return (unsigned short)r;
}
__device__ __forceinline__ float bf2f(unsigned short s) {
    return __builtin_bit_cast(float, ((unsigned)s) << 16);
}

__device__ __forceinline__ void gld16(const unsigned short* g, unsigned short* l) {
    __builtin_amdgcn_global_load_lds(
        (const __attribute__((address_space(1))) unsigned int*)g,
        (__attribute__((address_space(3))) unsigned int*)l, 16, 0, 0);
}

__global__ void sentinel_k(float* out, float v) { out[0] = v; }

// ---------------- tiled implicit-GEMM conv1d (fp32, spectro stem) ----------------
template<int KS, int SPAN, int ACT>
__global__ __launch_bounds__(256) void conv1d_t(
    const float* __restrict__ in, const float* __restrict__ wt,
    const float* __restrict__ bias, float* __restrict__ out,
    int IC, int Tin, int Tout, int stride, int dil, int pad) {
    __shared__ float Ws[16][KS][65];
    __shared__ float Gs[16][SPAN];
    int tid = threadIdx.x;
    int t0 = blockIdx.x * 64;
    int oc0 = blockIdx.y * 64;
    int b = blockIdx.z;
    int tx = tid & 15, ty = tid >> 4;
    float acc[4][4] = {{0.f}};
    int tbase = t0 * stride - pad;
    for (int ic0 = 0; ic0 < IC; ic0 += 16) {
        for (int idx = tid; idx < 64 * 16 * KS; idx += 256) {
            int o = idx / (16 * KS); int r = idx - o * 16 * KS;
            int i = r / KS; int j = r - i * KS;
            Ws[i][j][o] = wt[(size_t)(oc0 + o) * IC * KS + (size_t)(ic0 + i) * KS + j];
        }
        for (int idx = tid; idx < 16 * SPAN; idx += 256) {
            int i = idx / SPAN; int s = idx - i * SPAN;
            int ti = tbase + s;
            Gs[i][s] = (ti >= 0 && ti < Tin) ? in[((size_t)b * IC + ic0 + i) * Tin + ti] : 0.f;
        }
        __syncthreads();
#pragma unroll
        for (int i = 0; i < 16; i++) {
            float wv[4][KS];
#pragma unroll
            for (int o = 0; o < 4; o++)
#pragma unroll
                for (int j = 0; j < KS; j++) wv[o][j] = Ws[i][j][ty * 4 + o];
#pragma unroll
            for (int tj = 0; tj < 4; tj++) {
                int gb = (tx * 4 + tj) * stride;
#pragma unroll
                for (int j = 0; j < KS; j++) {
                    float g = Gs[i][gb + j * dil];
#pragma unroll
                    for (int o = 0; o < 4; o++) acc[o][tj] += wv[o][j] * g;
                }
            }
        }
        __syncthreads();
    }
#pragma unroll
    for (int o = 0; o < 4; o++) {
        int oc = oc0 + ty * 4 + o;
        float bz = bias[oc];
#pragma unroll
        for (int tj = 0; tj < 4; tj++) {
            int t = t0 + tx * 4 + tj;
            if (t < Tout) {
                float v = acc[o][tj] + bz;
                if (ACT == 1) v = gelu_f(v);
                out[((size_t)b * DIMSN + oc) * Tout + t] = v;
            }
        }
    }
}

// ------------- waveform stem pipeline -------------
__global__ void wcvt_k(const float* __restrict__ w2, unsigned short* __restrict__ wb2) {
    int idx = blockIdx.x * 256 + threadIdx.x;           // 5*1024*1024
    int j = idx >> 20;
    int rest = idx & 1048575;
    int oc = rest >> 10, ic = rest & 1023;
    wb2[idx] = f2bf(w2[((size_t)oc * 1024 + ic) * 5 + j]);
}

__global__ __launch_bounds__(256) void we1_bf_k(
    const float* __restrict__ wav, const float* __restrict__ w1,
    const float* __restrict__ b1, unsigned short* __restrict__ G1e, int t1base) {
    int idx = blockIdx.x * 256 + threadIdx.x;           // 2*3768*1024
    if (idx >= 2 * 3768 * 1024) return;
    int ic = idx & 1023;
    int rest = idx >> 10;
    int r = rest % 3768;
    int b = rest / 3768;
    int t1 = t1base + r;
    float g = 0.f;
    if (t1 >= 0 && t1 < 30000) {
        float acc = b1[ic];
        const float* wv = wav + (size_t)b * 150000;
        int base = t1 * 5 - 5;
#pragma unroll
        for (int j = 0; j < 11; j++) {
            int ti = base + j;
            if (ti >= 0 && ti < 150000) acc += w1[ic * 11 + j] * wv[ti];
        }
        g = gelu_f(acc);
    }
    G1e[idx] = f2bf(g);
}

__global__ __launch_bounds__(256) void conv2_mfma_k(
    const unsigned short* __restrict__ G1e, const unsigned short* __restrict__ wb2,
    const float* __restrict__ b2, unsigned short* __restrict__ G2e, int len) {
    __shared__ unsigned short Al[4096];
    __shared__ unsigned short Wl[4096];
    int tid = threadIdx.x;
    int tt0 = blockIdx.x * 128;
    int oc0 = blockIdx.y * 128;
    int b = blockIdx.z;
    int lane = tid & 63, w = tid >> 6;
    int wm = (w >> 1) * 64, wn = (w & 1) * 64;
    f32x4 z = {0.f, 0.f, 0.f, 0.f};
    f32x4 acc[4][4];
#pragma unroll
    for (int i = 0; i < 4; i++)
#pragma unroll
        for (int j = 0; j < 4; j++) acc[i][j] = z;
    int c1 = tid, c2 = tid + 256;
    int kg1 = c1 >> 7, m1 = c1 & 127, kg2 = c2 >> 7, m2 = c2 & 127;
    int tA1 = tt0 + m1; if (tA1 > len - 1) tA1 = len - 1;
    int tA2 = tt0 + m2; if (tA2 > len - 1) tA2 = len - 1;
    for (int j = 0; j < 5; j++) {
        for (int ic0 = 0; ic0 < 1024; ic0 += 32) {
            int r1 = 2 * tA1 + j, r2 = 2 * tA2 + j;
            gld16(G1e + ((size_t)(b * 3768 + r1) * 1024 + ic0 + kg1 * 8), &Al[c1 * 8]);
            gld16(G1e + ((size_t)(b * 3768 + r2) * 1024 + ic0 + kg2 * 8), &Al[c2 * 8]);
            gld16(wb2 + ((size_t)((j << 10) + oc0 + m1) * 1024 + ic0 + kg1 * 8), &Wl[c1 * 8]);
            gld16(wb2 + ((size_t)((j << 10) + oc0 + m2) * 1024 + ic0 + kg2 * 8), &Wl[c2 * 8]);
            __syncthreads();
            const unsigned short* Ab = &Al[(((lane >> 4) * 128) + wm + (lane & 15)) * 8];
            const unsigned short* Wb = &Wl[(((lane >> 4) * 128) + wn + (lane & 15)) * 8];
            short8b af[4], bfv[4];
#pragma unroll
            for (int i = 0; i < 4; i++) af[i] = *(const short8b*)(Ab + i * 128);
#pragma unroll
            for (int i = 0; i < 4; i++) bfv[i] = *(const short8b*)(Wb + i * 128);
#pragma unroll
            for (int mt = 0; mt < 4; mt++)
#pragma unroll
                for (int nt = 0; nt < 4; nt++)
                    acc[mt][nt] = __builtin_amdgcn_mfma_f32_16x16x32_bf16(
                        af[mt], bfv[nt], acc[mt][nt], 0, 0, 0);
            __syncthreads();
        }
    }
    int r4 = (lane >> 4) * 4, cn = lane & 15;
#pragma unroll
    for (int nt = 0; nt < 4; nt++) {
        int oc = oc0 + wn + nt * 16 + cn;
        float bz = b2[oc];
#pragma unroll
        for (int mt = 0; mt < 4; mt++)
#pragma unroll
            for (int rr = 0; rr < 4; rr++) {
                int tt = tt0 + wm + mt * 16 + r4 + rr;
                if (tt < len)
                    G2e[((size_t)b * 1880 + tt) * 1024 + oc] = f2bf(gelu_f(acc[mt][nt][rr] + bz));
            }
    }
}

// mean over 10 t2 -> P[b][ct][oc] bf16
__global__ void pool_k(const unsigned short* __restrict__ G2e, unsigned short* __restrict__ P,
                       int clen, int ct0) {
    int idx = blockIdx.x * 256 + threadIdx.x;           // 2*clen*1024
    int oc = idx & 1023;
    int rest = idx >> 10;
    int cl = rest % clen;
    int b = rest / clen;
    if (b >= 2) return;
    const unsigned short* g = G2e + ((size_t)b * 1880 + cl * 10) * 1024 + oc;
    float s = 0.f;
#pragma unroll
    for (int i = 0; i < 10; i++) s += bf2f(g[i * 1024]);
    P[((size_t)(b * CTXN) + ct0 + cl) * 1024 + oc] = f2bf(s * 0.1f);
}

// ---------------- MFMA GEMM ----------------
__global__ __launch_bounds__(256) void gemm_mfma_k(
    const unsigned short* __restrict__ A, const float* __restrict__ W,
    const float* __restrict__ bias, const float* __restrict__ res1,
    const float* __restrict__ res2, void* __restrict__ C,
    int M, int N, int K, int act, int outbf) {
    __shared__ unsigned short Al[4096];
    __shared__ unsigned short Wl[4096];
    int tid = threadIdx.x;
    int n0 = blockIdx.x * 128, m0 = blockIdx.y * 128;
    int lane = tid & 63, w = tid >> 6;
    int wm = (w >> 1) * 64, wn = (w & 1) * 64;
    f32x4 z = {0.f, 0.f, 0.f, 0.f};
    f32x4 acc[4][4];
#pragma unroll
    for (int i = 0; i < 4; i++)
#pragma unroll
        for (int j = 0; j < 4; j++) acc[i][j] = z;
    int c1 = tid, c2 = tid + 256;
    int kg1 = c1 >> 7, m1 = c1 & 127, kg2 = c2 >> 7, m2 = c2 & 127;
    int ra1 = m0 + m1; if (ra1 > M - 1) ra1 = M - 1;
    int ra2 = m0 + m2; if (ra2 > M - 1) ra2 = M - 1;
    for (int k0 = 0; k0 < K; k0 += 32) {
        gld16(A + (size_t)ra1 * K + k0 + kg1 * 8, &Al[c1 * 8]);
        gld16(A + (size_t)ra2 * K + k0 + kg2 * 8, &Al[c2 * 8]);
        {
            const float* wp = W + (size_t)(n0 + m1) * K + k0 + kg1 * 8;
            float4 fa = *(const float4*)wp;
            float4 fb = *(const float4*)(wp + 4);
            short8b v;
            v[0] = (short)f2bf(fa.x); v[1] = (short)f2bf(fa.y);
            v[2] = (short)f2bf(fa.z); v[3] = (short)f2bf(fa.w);
            v[4] = (short)f2bf(fb.x); v[5] = (short)f2bf(fb.y);
            v[6] = (short)f2bf(fb.z); v[7] = (short)f2bf(fb.w);
            *(short8b*)&Wl[c1 * 8] = v;
            wp = W + (size_t)(n0 + m2) * K + k0 + kg2 * 8;
            fa = *(const float4*)wp;
            fb = *(const float4*)(wp + 4);
            v[0] = (short)f2bf(fa.x); v[1] = (short)f2bf(fa.y);
            v[2] = (short)f2bf(fa.z); v[3] = (short)f2bf(fa.w);
            v[4] = (short)f2bf(fb.x); v[5] = (short)f2bf(fb.y);
            v[6] = (short)f2bf(fb.z); v[7] = (short)f2bf(fb.w);
            *(short8b*)&Wl[c2 * 8] = v;
        }
        __syncthreads();
        const unsigned short* Ab = &Al[(((lane >> 4) * 128) + wm + (lane & 15)) * 8];
        const unsigned short* Wb = &Wl[(((lane >> 4) * 128) + wn + (lane & 15)) * 8];
        short8b af[4], bfv[4];
#pragma unroll
        for (int i = 0; i < 4; i++) af[i] = *(const short8b*)(Ab + i * 128);
#pragma unroll
        for (int i = 0; i < 4; i++) bfv[i] = *(const short8b*)(Wb + i * 128);
#pragma unroll
        for (int mt = 0; mt < 4; mt++)
#pragma unroll
            for (int nt = 0; nt < 4; nt++)
                acc[mt][nt] = __builtin_amdgcn_mfma_f32_16x16x32_bf16(
                    af[mt], bfv[nt], acc[mt][nt], 0, 0, 0);
        __syncthreads();
    }
    int r4 = (lane >> 4) * 4, cn = lane & 15;
#pragma unroll
    for (int nt = 0; nt < 4; nt++) {
        int n = n0 + wn + nt * 16 + cn;
        float bz = bias ? bias[n] : 0.f;
#pragma unroll
        for (int mt = 0; mt < 4; mt++)
#pragma unroll
            for (int rr = 0; rr < 4; rr++) {
                int m = m0 + wm + mt * 16 + r4 + rr;
                if (m >= M) continue;
                float v = acc[mt][nt][rr] + bz;
                if (act) v = fmaxf(v, 0.f);
                size_t off = (size_t)m * N + n;
                if (res1) v += res1[off];
                if (res2) v += res2[off];
                if (outbf) ((unsigned short*)C)[off] = f2bf(v);
                else ((float*)C)[off] = v;
            }
    }
}

// ---------------- small elementwise / stem kernels ----------------
__global__ void dwconv_k(const float* __restrict__ in, const float* __restrict__ w3,
                         const float* __restrict__ b3, float* __restrict__ out) {
    int idx = blockIdx.x * 256 + threadIdx.x;           // 2*1024*1500
    int t = idx % CTXN;
    int bc = idx / CTXN;
    int c = bc & 1023;
    float acc = b3[c];
#pragma unroll
    for (int j = 0; j < 3; j++) {
        int ti = t - 1 + j;
        if (ti >= 0 && ti < CTXN) acc += w3[c * 3 + j] * in[(size_t)bc * CTXN + ti];
    }
    out[idx] = acc;
}

__global__ void se_mean_k(const float* __restrict__ in, float* __restrict__ y0) {
    int bc = blockIdx.x; int lane = threadIdx.x;        // 64
    float acc = 0.f;
    for (int t = lane; t < CTXN; t += 64) acc += in[(size_t)bc * CTXN + t];
#pragma unroll
    for (int off = 32; off > 0; off >>= 1) acc += __shfl_xor(acc, off);
    if (lane == 0) y0[bc] = acc / 1500.f;
}

__global__ void se_fc1_k(const float* __restrict__ y0, const float* __restrict__ w,
                         const float* __restrict__ b, float* __restrict__ y1) {
    int tid = threadIdx.x;                               // 128 = 2b x 64n
    int bb = tid >> 6, n = tid & 63;
    float acc = b[n];
    for (int k = 0; k < 1024; k++) acc += y0[bb * 1024 + k] * w[n * 1024 + k];
    y1[bb * 64 + n] = fmaxf(acc, 0.f);
}

__global__ void se_fc2_k(const float* __restrict__ y1, const float* __restrict__ w,
                         const float* __restrict__ b, float* __restrict__ y2) {
    int idx = blockIdx.x * 256 + threadIdx.x;            // 2048
    int bb = idx >> 10, c = idx & 1023;
    float acc = b[c];
#pragma unroll
    for (int k = 0; k < 64; k++) acc += y1[bb * 64 + k] * w[c * 64 + k];
    y2[idx] = 1.f / (1.f + expf(-acc));
}

__global__ void se_scale_k(const float* __restrict__ in, const float* __restrict__ y2,
                           float* __restrict__ out) {
    int idx = blockIdx.x * 256 + threadIdx.x;            // 2*1024*1500
    int bc = idx / CTXN;
    out[idx] = gelu_f(in[idx] * y2[bc]);
}

// h[b,t,d] = blend*xs[b,d,t] + (1-blend)*P[b,t,d] + sinusoid(t,d)
__global__ void blend_k(const float* __restrict__ H6, const unsigned short* __restrict__ P,
                        const float* __restrict__ bsw, float* __restrict__ Hs) {
    int idx = blockIdx.x * 256 + threadIdx.x;            // 2*1500*1024
    int d = idx & 1023;
    int rest = idx >> 10;                                // b*1500 + t
    int t = rest % CTXN;
    int b = rest / CTXN;
    float xs = H6[((size_t)b * DIMSN + d) * CTXN + t];
    float wsv = bf2f(P[idx]);
    float bl = 1.f / (1.f + expf(-bsw[0]));
    float pos;
    if (d < 512) {
        float inv = expf(-0.018024149455921103f * (float)d);
        pos = sinf((float)t * inv);
    } else {
        float inv = expf(-0.018024149455921103f * (float)(d - 512));
        pos = cosf((float)t * inv);
    }
    Hs[idx] = bl * xs + (1.f - bl) * wsv + pos;
}

template<int OB>
__global__ __launch_bounds__(256) void rmsnorm_k(const float* __restrict__ X,
    const float* __restrict__ Wt, void* __restrict__ Y) {
    int row = blockIdx.x; int tid = threadIdx.x;
    const float* x = X + (size_t)row * DIMSN;
    float ss = 0.f;
    for (int d = tid; d < DIMSN; d += 256) { float v = x[d]; ss += v * v; }
    __shared__ float red[256];
    red[tid] = ss; __syncthreads();
    for (int s = 128; s > 0; s >>= 1) { if (tid < s) red[tid] += red[tid + s]; __syncthreads(); }
    float r = rsqrtf(red[0] / (float)DIMSN + 1e-8f);
    for (int d = tid; d < DIMSN; d += 256) {
        float v = x[d] * r * Wt[d];
        if (OB) ((unsigned short*)Y)[(size_t)row * DIMSN + d] = f2bf(v);
        else ((float*)Y)[(size_t)row * DIMSN + d] = v;
    }
}

// RoPE fp32 -> bf16 Q/K + per-key scale flag szf
__global__ void rope_bf_k(const float* __restrict__ Qp, const float* __restrict__ Kp,
                          const float* __restrict__ factor, int layer,
                          unsigned short* __restrict__ Qo, unsigned short* __restrict__ Ko,
                          float* __restrict__ szf) {
    int idx = blockIdx.x * 256 + threadIdx.x;            // 2*1500*16*32
    int d = idx & 31;
    int h = (idx >> 5) & 15;
    int row = idx >> 9;
    int t = row % CTXN;
    int b = row / CTXN;
    float inv = 1.0f / powf(10000.0f, (float)d / 32.0f);
    float fr = (float)t * inv;
    float sn, cs;
    sincosf(fr, &sn, &cs);
    size_t base = (size_t)row * DIMSN + h * 64 + d;
    float q1 = Qp[base], q2 = Qp[base + 32];
    Qo[base] = f2bf(q1 * cs - q2 * sn); Qo[base + 32] = f2bf(q1 * sn + q2 * cs);
    float k1 = Kp[base], k2 = Kp[base + 32];
    float kr0 = k1 * cs - k2 * sn;
    Ko[base] = f2bf(kr0); Ko[base + 32] = f2bf(k1 * sn + k2 * cs);
    if (d == 0) {
        float f = factor[layer];
        float zf = fminf(fmaxf(log1pf(expf(f)), 1e-5f), 0.1f);
        szf[(b * 16 + h) * 1500 + t] = (kr0 == 0.f) ? zf : 1.0f;
    }
}

// ---------------- MFMA flash attention ----------------
// S[q,k>q] := 0 (multiplicative mask semantics); full-row softmax over 1500 keys.
// Block: (q-tile 64, h, b); 4 waves x 16 q-rows. K-tiles of 64.
__global__ __launch_bounds__(256) void attn_mfma_k(
    const unsigned short* __restrict__ Qbf, const unsigned short* __restrict__ Kbf,
    const unsigned short* __restrict__ Vbf, const float* __restrict__ szf,
    unsigned short* __restrict__ Op) {
    __shared__ unsigned short Ks[4096];    // [key 64][hd slot^swz 8][8]
    __shared__ unsigned short Vts[4096];   // [d 64][k slot^swz 8][8] (transposed)
    __shared__ unsigned short Ps[4096];    // per-wave [q 16][k slot^swz 8][8]
    int tid = threadIdx.x;
    int q0 = blockIdx.x * 64, h = blockIdx.y, b = blockIdx.z;
    int lane = tid & 63, w = tid >> 6;
    int lg = lane >> 4, lr = lane & 15;
    // Q fragments (A): row = lr, k-group = lg (+32 per kk)
    short8b qf[2];
    {
        int qrow = q0 + w * 16 + lr; if (qrow > 1499) qrow = 1499;
        const unsigned short* qp = Qbf + ((size_t)(b * 1500 + qrow) << 10) + (h << 6) + lg * 8;
        qf[0] = *(const short8b*)qp;
        qf[1] = *(const short8b*)(qp + 32);
    }
    f32x4 z = {0.f, 0.f, 0.f, 0.f};
    f32x4 o[4];
#pragma unroll
    for (int nt = 0; nt < 4; nt++) o[nt] = z;
    float m_run[4], l_run[4];
#pragma unroll
    for (int r = 0; r < 4; r++) { m_run[r] = -3.0e38f; l_run[r] = 0.f; }
    const float* szp = szf + (b * 16 + h) * 1500;
    unsigned short* Pw = &Ps[w << 10];

    for (int jt = 0; jt < 24; jt++) {
        int j0 = jt << 6;
        __syncthreads();
        // stage K tile (gld16, source pre-swizzled per row)
#pragma unroll
        for (int it = 0; it < 2; it++) {
            int i = tid + it * 256;
            int r = i >> 3, s = i & 7;
            int jc = j0 + r; if (jc > 1499) jc = 1499;
            gld16(Kbf + ((size_t)(b * 1500 + jc) << 10) + (h << 6) + ((s ^ (r & 7)) << 3),
                  &Ks[i << 3]);
        }
        // stage V tile transposed (reg-staged, swizzled scatter)
#pragma unroll
        for (int it = 0; it < 2; it++) {
            int i = tid + it * 256;
            int k = i >> 3, d0 = (i & 7) << 3;
            int kc = j0 + k; if (kc > 1499) kc = 1499;
            short8b v = *(const short8b*)(Vbf + ((size_t)(b * 1500 + kc) << 10) + (h << 6) + d0);
#pragma unroll
            for (int j = 0; j < 8; j++) {
                int d = d0 + j;
                Vts[(d << 6) + ((((k >> 3) ^ (d & 7))) << 3) + (k & 7)] = (unsigned short)v[j];
            }
        }
        __syncthreads();
        // QK^T: S[q=lg*4+r][key=nt*16+lr]
        f32x4 s4[4];
#pragma unroll
        for (int nt = 0; nt < 4; nt++) {
            f32x4 s = z;
#pragma unroll
            for (int kk = 0; kk < 2; kk++) {
                short8b kf = *(const short8b*)&Ks[((nt * 16 + lr) << 6) +
                                                 ((((kk << 2) + lg) ^ (lr & 7)) << 3)];
                s = __builtin_amdgcn_mfma_f32_16x16x32_bf16(qf[kk], kf, s, 0, 0, 0);
            }
            s4[nt] = s;
        }
        // mask + scale
#pragma unroll
        for (int nt = 0; nt < 4; nt++) {
            int kg = j0 + nt * 16 + lr;
            float szv = (kg < 1500) ? szp[kg] : 1.f;
#pragma unroll
            for (int r = 0; r < 4; r++) {
                int qg = q0 + w * 16 + lg * 4 + r;
                float v = s4[nt][r] * 0.125f * szv;
                s4[nt][r] = (kg < 1500) ? ((kg <= qg) ? v : 0.f) : -3.0e38f;
            }
        }
        // online softmax per q-row (row spread over 16 lanes of same lg)
#pragma unroll
        for (int r = 0; r < 4; r++) {
            float tm = fmaxf(fmaxf(s4[0][r], s4[1][r]), fmaxf(s4[2][r], s4[3][r]));
            tm = fmaxf(tm, __shfl_xor(tm, 1));
            tm = fmaxf(tm, __shfl_xor(tm, 2));
            tm = fmaxf(tm, __shfl_xor(tm, 4));
            tm = fmaxf(tm, __shfl_xor(tm, 8));
            float mnew = fmaxf(m_run[r], tm);
            float c = expf(m_run[r] - mnew);
            m_run[r] = mnew;
            float ps = 0.f;
#pragma unroll
            for (int nt = 0; nt < 4; nt++) {
                float p = expf(s4[nt][r] - mnew);
                s4[nt][r] = p;
                ps += p;
            }
            ps += __shfl_xor(ps, 1);
            ps += __shfl_xor(ps, 2);
            ps += __shfl_xor(ps, 4);
            ps += __shfl_xor(ps, 8);
            l_run[r] = l_run[r] * c + ps;
#pragma unroll
            for (int nt = 0; nt < 4; nt++) o[nt][r] *= c;
        }
        // write P (bf16) to per-wave LDS in A-frag layout (swizzled)
#pragma unroll
        for (int nt = 0; nt < 4; nt++) {
            int ks = nt * 2 + (lr >> 3);
#pragma unroll
            for (int r = 0; r < 4; r++) {
                int q = lg * 4 + r;
                Pw[(q << 6) + ((ks ^ (q & 7)) << 3) + (lr & 7)] = f2bf(s4[nt][r]);
            }
        }
        // PV: O[q=lr... (A rows = lr)][d=nt*16+lr...]; accum layout matches (lg,r)->q
        short8b pf[2];
#pragma unroll
        for (int kk = 0; kk < 2; kk++)
            pf[kk] = *(const short8b*)&Pw[(lr << 6) + ((((kk << 2) + lg) ^ (lr & 7)) << 3)];
#pragma unroll
        for (int nt = 0; nt < 4; nt++) {
#pragma unroll
            for (int kk = 0; kk < 2; kk++) {
                short8b vf = *(const short8b*)&Vts[((nt * 16 + lr) << 6) +
                                                   ((((kk << 2) + lg) ^ (lr & 7)) << 3)];
                o[nt] = __builtin_amdgcn_mfma_f32_16x16x32_bf16(pf[kk], vf, o[nt], 0, 0, 0);
            }
        }
    }
    // epilogue: normalize and store bf16
#pragma unroll
    for (int r = 0; r < 4; r++) {
        int qg = q0 + w * 16 + lg * 4 + r;
        if (qg < 1500) {
            float rl = 1.f / l_run[r];
#pragma unroll
            for (int nt = 0; nt < 4; nt++)
                Op[((size_t)(b * 1500 + qg) << 10) + (h << 6) + nt * 16 + lr] =
                    f2bf(o[nt][r] * rl);
        }
    }
}

// ---------------- launch ----------------
extern "C" void kernel_launch(void* const* d_in, const int* in_sizes, int n_in,
                              void* d_out, int out_size, void* d_ws, size_t ws_size,
                              hipStream_t stream) {
    const float* x      = (const float*)d_in[0];
    const float* wav    = (const float*)d_in[1];
    const float* se_w1  = (const float*)d_in[2];
    const float* se_b1  = (const float*)d_in[3];
    const float* se_w2  = (const float*)d_in[4];
    const float* se_b2  = (const float*)d_in[5];
    const float* se_w3  = (const float*)d_in[6];
    const float* se_b3  = (const float*)d_in[7];
    const float* se_w4  = (const float*)d_in[8];
    const float* se_b4  = (const float*)d_in[9];
    const float* se_fc1w = (const float*)d_in[10];
    const float* se_fc1b = (const float*)d_in[11];
    const float* se_fc2w = (const float*)d_in[12];
    const float* se_fc2b = (const float*)d_in[13];
    const float* se_w5  = (const float*)d_in[14];
    const float* se_b5  = (const float*)d_in[15];
    const float* we_w1  = (const float*)d_in[16];
    const float* we_b1  = (const float*)d_in[17];
    const float* we_w2  = (const float*)d_in[18];
    const float* we_b2  = (const float*)d_in[19];
    const float* qw     = (const float*)d_in[20];
    const float* qb     = (const float*)d_in[21];
    const float* kw     = (const float*)d_in[22];
    const float* vw     = (const float*)d_in[23];
    const float* vb     = (const float*)d_in[24];
    const float* ow     = (const float*)d_in[25];
    const float* ob     = (const float*)d_in[26];
    const float* factor = (const float*)d_in[27];
    const float* lna    = (const float*)d_in[28];
    const float* lnc    = (const float*)d_in[29];
    const float* m1w    = (const float*)d_in[30];
    const float* m1b    = (const float*)d_in[31];
    const float* m2w    = (const float*)d_in[32];
    const float* m2b    = (const float*)d_in[33];
    const float* lnE    = (const float*)d_in[34];
    const float* bsw    = (const float*)d_in[35];

    float* ws = (float*)d_ws;
    // transformer-phase layout (float-unit offsets)
    float* H   = ws;                                          // 0      .. 3.072M
    float* H1  = ws + 3072000;                                // 3.072  .. 6.144M
    unsigned short* Ubf = (unsigned short*)(ws + 6144000);    // 6.144  .. 7.680M
    float* Qb_ = ws + 7680000;                                // 7.680  .. 10.752M
    float* Kb_ = ws + 10752000;                               // 10.752 .. 13.824M
    unsigned short* Qbf = (unsigned short*)(ws + 13824000);   // 13.824 .. 15.360M
    unsigned short* Kbf = (unsigned short*)(ws + 15360000);   // 15.360 .. 16.896M
    unsigned short* Vbf = (unsigned short*)(ws + 16896000);   // 16.896 .. 18.432M
    unsigned short* Pbf = (unsigned short*)(ws + 18432000);   // 18.432 .. 19.968M
    float* szf = ws + 19968000;                               // 48000 f
    float* SM  = ws + 20016000;                               // SE small
    float* Y0 = SM, *Y1 = SM + 2048, *Y2 = SM + 2176;
    unsigned short* M1bf = (unsigned short*)Qb_;              // 6.144M f (Qb_+Kb_)
    // stem-phase aliases (disjoint in time)
    unsigned short* G2e = (unsigned short*)H;                 // 3.85M u16 <= 6.144M u16
    float* SPA = H1;
    float* SPB = ws + 6144000;                                // 6.144 .. 9.216M
    unsigned short* wb2 = (unsigned short*)(ws + 9216000);    // 5.24M u16, 9.216..11.84M
    unsigned short* G1e = (unsigned short*)(ws + 13824000);   // 7.716M u16, 13.824..17.682M

    const size_t NEED = (size_t)(20016000 + 8192) * sizeof(float);   // ~80.1 MB
    if (ws_size < NEED) {
        sentinel_k<<<1, 1, 0, stream>>>((float*)d_out, (float)ws_size);
        return;
    }

    // ---- waveform stem (8 time-chunks) ----
    wcvt_k<<<20480, 256, 0, stream>>>(we_w2, wb2);
    for (int e = 0; e < 8; e++) {
        int len = (e == 7) ? 1840 : 1880;
        int t1base = 3760 * e - 2;
        we1_bf_k<<<30144, 256, 0, stream>>>(wav, we_w1, we_b1, G1e, t1base);
        conv2_mfma_k<<<dim3(15, 8, 2), 256, 0, stream>>>(G1e, wb2, we_b2, G2e, len);
        int clen = len / 10;
        pool_k<<<(2 * clen * 1024) / 256, 256, 0, stream>>>(G2e, Pbf, clen, e * 188);
    }
    // ---- spectrogram stem ----
    dim3 cgrid(24, 16, 2);
    conv1d_t<3, 66, 1><<<cgrid, 256, 0, stream>>>(x,   se_w1, se_b1, SPA, 128,  1500, 1500, 1, 1, 1);
    conv1d_t<3, 68, 0><<<cgrid, 256, 0, stream>>>(SPA, se_w2, se_b2, SPB, 1024, 1500, 1500, 1, 2, 2);
    dwconv_k<<<12000, 256, 0, stream>>>(SPB, se_w3, se_b3, SPA);
    conv1d_t<1, 64, 0><<<cgrid, 256, 0, stream>>>(SPA, se_w4, se_b4, SPB, 1024, 1500, 1500, 1, 1, 0);
    se_mean_k<<<2048, 64, 0, stream>>>(SPB, Y0);
    se_fc1_k<<<1, 128, 0, stream>>>(Y0, se_fc1w, se_fc1b, Y1);
    se_fc2_k<<<8, 256, 0, stream>>>(Y1, se_fc2w, se_fc2b, Y2);
    se_scale_k<<<12000, 256, 0, stream>>>(SPB, Y2, SPA);
    conv1d_t<3, 66, 0><<<cgrid, 256, 0, stream>>>(SPA, se_w5, se_b5, SPB, 1024, 1500, 1500, 1, 1, 1);
    // blend + sinusoids -> H [B,CTX,D]
    blend_k<<<12000, 256, 0, stream>>>(SPB, Pbf, bsw, H);

    // ---- transformer ----
    for (int L = 0; L < 4; L++) {
        rmsnorm_k<1><<<3000, 256, 0, stream>>>(H, lna + L * 1024, Ubf);
        gemm_mfma_k<<<dim3(8, 24), 256, 0, stream>>>(Ubf, qw + (size_t)L * 1048576, qb + L * 1024,
                                                     nullptr, nullptr, Qb_, 3000, 1024, 1024, 0, 0);
        gemm_mfma_k<<<dim3(8, 24), 256, 0, stream>>>(Ubf, kw + (size_t)L * 1048576, nullptr,
                                                     nullptr, nullptr, Kb_, 3000, 1024, 1024, 0, 0);
        gemm_mfma_k<<<dim3(8, 24), 256, 0, stream>>>(Ubf, vw + (size_t)L * 1048576, vb + L * 1024,
                                                     nullptr, nullptr, Vbf, 3000, 1024, 1024, 0, 1);
        rope_bf_k<<<6000, 256, 0, stream>>>(Qb_, Kb_, factor, L, Qbf, Kbf, szf);
        attn_mfma_k<<<dim3(24, 16, 2), 256, 0, stream>>>(Qbf, Kbf, Vbf, szf, Ubf);
        gemm_mfma_k<<<dim3(8, 24), 256, 0, stream>>>(Ubf, ow + (size_t)L * 1048576, ob + L * 1024,
                                                     H, nullptr, H1, 3000, 1024, 1024, 0, 0);
        rmsnorm_k<1><<<3000, 256, 0, stream>>>(H1, lnc + L * 1024, Ubf);
        gemm_mfma_k<<<dim3(32, 24), 256, 0, stream>>>(Ubf, m1w + (size_t)L * 4194304, m1b + L * 4096,
                                                      nullptr, nullptr, M1bf, 3000, 4096, 1024, 1, 1);
        gemm_mfma_k<<<dim3(8, 24), 256, 0, stream>>>(M1bf, m2w + (size_t)L * 4194304, m2b + L * 1024,
                                                     H1, H, H, 3000, 1024, 4096, 0, 0);
    }
    rmsnorm_k<0><<<3000, 256, 0, stream>>>(H, lnE, (float*)d_out);
}